// Round 5
// baseline (154.388 us; speedup 1.0000x reference)
//
#include <hip/hip_runtime.h>
#include <hip/hip_bf16.h>

#define BD 8192
#define DD 1024
#define BM 128
#define BN 128
#define BKK 64

typedef __attribute__((ext_vector_type(8))) short short8;
typedef __attribute__((ext_vector_type(4))) float floatx4;

__device__ inline float bf2f(unsigned short u) {
    union { unsigned int u; float f; } un;
    un.u = ((unsigned int)u) << 16;
    return un.f;
}
__device__ inline unsigned short f2bf(float f) {
    union { float f; unsigned int u; } un;
    un.f = f;
    unsigned int u = un.u;
    u += 0x7FFF + ((u >> 16) & 1);   // round-to-nearest-even
    return (unsigned short)(u >> 16);
}

__device__ inline void gld_lds16(const void* g, void* l) {
    __builtin_amdgcn_global_load_lds(
        (const __attribute__((address_space(1))) unsigned int*)g,
        (__attribute__((address_space(3))) unsigned int*)l, 16, 0, 0);
}

// All three normalizations in one launch. Wave-per-row (64 lanes x 4 float4 = 1024 f32).
// blocks [0,2048): z_rna -> rnb (+entropy er), [2048,4096): z_atac -> anb (+ea),
// [4096,4352): link -> linkb (no entropy).
__global__ __launch_bounds__(256) void norm_all(const float* __restrict__ rna,
                                                const float* __restrict__ atac,
                                                const float* __restrict__ link,
                                                unsigned short* __restrict__ rnb,
                                                unsigned short* __restrict__ anb,
                                                unsigned short* __restrict__ linkb,
                                                float* __restrict__ er,
                                                float* __restrict__ ea) {
    int bid = blockIdx.x;
    int wid = threadIdx.x >> 6, lane = threadIdx.x & 63;
    const float* x;
    unsigned short* xb;
    float* ep;
    int row;
    bool ent = true;
    if (bid < 2048)      { x = rna;  xb = rnb;   ep = er + bid;          row = bid * 4 + wid; }
    else if (bid < 4096) { x = atac; xb = anb;   ep = ea + (bid - 2048); row = (bid - 2048) * 4 + wid; }
    else                 { x = link; xb = linkb; ep = nullptr;           row = (bid - 4096) * 4 + wid; ent = false; }

    const float4* xr = (const float4*)(x + (size_t)row * DD);
    float4 v0 = xr[lane];
    float4 v1 = xr[lane + 64];
    float4 v2 = xr[lane + 128];
    float4 v3 = xr[lane + 192];
    float ss = v0.x*v0.x + v0.y*v0.y + v0.z*v0.z + v0.w*v0.w
             + v1.x*v1.x + v1.y*v1.y + v1.z*v1.z + v1.w*v1.w
             + v2.x*v2.x + v2.y*v2.y + v2.z*v2.z + v2.w*v2.w
             + v3.x*v3.x + v3.y*v3.y + v3.z*v3.z + v3.w*v3.w;
#pragma unroll
    for (int off = 1; off < 64; off <<= 1) ss += __shfl_xor(ss, off);
    float inv = 1.0f / fmaxf(sqrtf(ss), 1e-12f);
    ushort4* orow = (ushort4*)(xb + (size_t)row * DD);
    float4 vv[4] = {v0, v1, v2, v3};
    float epart = 0.f;
#pragma unroll
    for (int i = 0; i < 4; ++i) {
        float a = vv[i].x * inv, b = vv[i].y * inv, c = vv[i].z * inv, d = vv[i].w * inv;
        ushort4 o;
        o.x = f2bf(a); o.y = f2bf(b); o.z = f2bf(c); o.w = f2bf(d);
        orow[lane + 64 * i] = o;
        if (ent) {
            epart += a * __logf(a + 1e-8f) + b * __logf(b + 1e-8f)
                   + c * __logf(c + 1e-8f) + d * __logf(d + 1e-8f);
        }
    }
    if (ent) {
#pragma unroll
        for (int off = 1; off < 64; off <<= 1) epart += __shfl_xor(epart, off);
        __shared__ float sw[4];
        if (lane == 0) sw[wid] = epart;
        __syncthreads();
        if (threadIdx.x == 0) ep[0] = sw[0] + sw[1] + sw[2] + sw[3];
    }
}

// Split-K GEMM + fused sum epilogue + last-block-done finalize (no separate kernel).
__global__ __launch_bounds__(256) void gemm_cos(const unsigned short* __restrict__ anb,
                                                const unsigned short* __restrict__ linkb,
                                                const unsigned short* __restrict__ rnb,
                                                float* __restrict__ gpart,
                                                const float* __restrict__ er,
                                                const float* __restrict__ ea,
                                                const float* __restrict__ temp,
                                                unsigned int* __restrict__ ctr,
                                                float* __restrict__ out) {
    __shared__ unsigned short As[BM * BKK];
    __shared__ unsigned short Bs[BN * BKK];
    __shared__ float swb[4];

    // 1024 blocks = 64 btiles x 8 itiles x 2 ksplits; bid&7 = XCD.
    int bid = blockIdx.x;
    int j = bid >> 3;
    int btile = (bid & 7) * 8 + (j & 7);
    int itile = (j >> 3) & 7;
    int ks = j >> 6;
    int b0 = btile * BM;
    int i0 = itile * BN;
    int kbase = ks * 512;

    int tid = threadIdx.x;
    int wid = tid >> 6, lane = tid & 63;
    int wm = wid >> 1, wn = wid & 1;
    int r = lane & 15, kg = lane >> 4;

    // Staging: LDS linear dest; global source column pre-swizzled (rule 21).
    int srow = tid >> 3;
    int scb = (tid & 7) * 16;
    int scb_src = scb ^ ((srow & 7) << 4);

    const char* agbase = (const char*)anb + ((size_t)(b0 + srow) * DD + kbase) * 2 + scb_src;
    const char* bgbase = (const char*)linkb + ((size_t)(i0 + srow) * DD + kbase) * 2 + scb_src;
    unsigned short* al = As + srow * BKK + scb / 2;
    unsigned short* bl = Bs + srow * BKK + scb / 2;

    floatx4 acc[4][4];
#pragma unroll
    for (int m = 0; m < 4; ++m)
#pragma unroll
        for (int n = 0; n < 4; ++n) acc[m][n] = (floatx4)0.0f;

#pragma unroll
    for (int c = 0; c < 4; ++c) {
        gld_lds16(agbase + (size_t)c * 32 * DD * 2, al + c * 2048);
        gld_lds16(bgbase + (size_t)c * 32 * DD * 2, bl + c * 2048);
    }

    for (int step = 0; step < 8; ++step) {
        __syncthreads();
#pragma unroll
        for (int kk = 0; kk < 2; ++kk) {
            short8 a_[4], b_[4];
#pragma unroll
            for (int m = 0; m < 4; ++m) {
                int row = wm * 64 + m * 16 + r;
                int cb = (kg * 16 + kk * 64) ^ ((row & 7) << 4);
                a_[m] = *(const short8*)((const char*)As + row * 128 + cb);
            }
#pragma unroll
            for (int n = 0; n < 4; ++n) {
                int row = wn * 64 + n * 16 + r;
                int cb = (kg * 16 + kk * 64) ^ ((row & 7) << 4);
                b_[n] = *(const short8*)((const char*)Bs + row * 128 + cb);
            }
#pragma unroll
            for (int m = 0; m < 4; ++m)
#pragma unroll
                for (int n = 0; n < 4; ++n)
                    acc[m][n] = __builtin_amdgcn_mfma_f32_16x16x32_bf16(a_[m], b_[n], acc[m][n], 0, 0, 0);
        }
        __syncthreads();
        if (step < 7) {
            size_t kb = (size_t)(step + 1) * BKK * 2;
#pragma unroll
            for (int c = 0; c < 4; ++c) {
                gld_lds16(agbase + (size_t)c * 32 * DD * 2 + kb, al + c * 2048);
                gld_lds16(bgbase + (size_t)c * 32 * DD * 2 + kb, bl + c * 2048);
            }
        }
    }

    int b0w = b0 + wm * 64, i0w = i0 + wn * 64;
    float s = 0.f;
#pragma unroll
    for (int m = 0; m < 4; ++m) {
#pragma unroll
        for (int rr = 0; rr < 4; ++rr) {
            const unsigned short* rrow = rnb + (size_t)(b0w + m * 16 + kg * 4 + rr) * DD + i0w + r;
#pragma unroll
            for (int n = 0; n < 4; ++n)
                s += acc[m][n][rr] * bf2f(rrow[n * 16]);
        }
    }
#pragma unroll
    for (int off = 1; off < 64; off <<= 1) s += __shfl_xor(s, off);
    if (lane == 0) swb[wid] = s;
    __syncthreads();

    // ---- last-block-done finalize ----
    __shared__ unsigned int is_last;
    if (tid == 0) {
        gpart[bid] = swb[0] + swb[1] + swb[2] + swb[3];
        __threadfence();                       // make gpart[bid] device-visible
        is_last = (atomicAdd(ctr, 1u) == 1023u);
    }
    __syncthreads();
    if (!is_last) return;
    __threadfence();                           // acquire: see all gpart writes

    __shared__ float swc[12];
    float t_s = 0.f, t_e = 0.f, t_a = 0.f;
    for (int i = tid; i < 1024; i += 256) t_s += gpart[i];
    for (int i = tid; i < 2048; i += 256) { t_e += er[i]; t_a += ea[i]; }
#pragma unroll
    for (int off = 1; off < 64; off <<= 1) {
        t_s += __shfl_xor(t_s, off);
        t_e += __shfl_xor(t_e, off);
        t_a += __shfl_xor(t_a, off);
    }
    if (lane == 0) { swc[wid * 3] = t_s; swc[wid * 3 + 1] = t_e; swc[wid * 3 + 2] = t_a; }
    __syncthreads();
    if (tid == 0) {
        float total = swc[0] + swc[3] + swc[6] + swc[9];
        float ser = swc[1] + swc[4] + swc[7] + swc[10];
        float sea = swc[2] + swc[5] + swc[8] + swc[11];
        float ent_rna = -ser / (float)BD;
        float ent_atac = -sea / (float)BD;
        float avg = 0.5f * (ent_rna + ent_atac);
        float t = temp[0];
        float sg = 1.0f / (1.0f + __expf(-t));
        float scale = sg * 0.1f + (1.0f - sg) * avg;
        float tau = fminf(fmaxf(scale, 0.01f), 1.0f);
        out[0] = -(total / (float)BD) / tau;
    }
}

extern "C" void kernel_launch(void* const* d_in, const int* in_sizes, int n_in,
                              void* d_out, int out_size, void* d_ws, size_t ws_size,
                              hipStream_t stream) {
    const float* z_rna = (const float*)d_in[0];
    const float* z_atac = (const float*)d_in[1];
    const float* link = (const float*)d_in[2];
    const float* temp = (const float*)d_in[3];
    float* out = (float*)d_out;

    char* ws = (char*)d_ws;
    float* gpart = (float*)ws;                          // 1024 f32
    float* er_part = (float*)(ws + 4096);               // 2048 f32
    float* ea_part = (float*)(ws + 12288);              // 2048 f32
    unsigned int* ctr = (unsigned int*)(ws + 20480);    // 1 u32
    unsigned short* linkb = (unsigned short*)(ws + 32768);                       // 2 MB
    unsigned short* rnb = (unsigned short*)(ws + 32768 + 2097152);               // 16 MB
    unsigned short* anb = (unsigned short*)(ws + 32768 + 2097152 + 16777216);    // 16 MB

    hipMemsetAsync(ctr, 0, 4, stream);   // counter must start at 0 (ws is poisoned)
    norm_all<<<4352, 256, 0, stream>>>(z_rna, z_atac, link, rnb, anb, linkb, er_part, ea_part);
    gemm_cos<<<1024, 256, 0, stream>>>(anb, linkb, rnb, gpart, er_part, ea_part, temp, ctr, out);
}

// Round 6
// 133.162 us; speedup vs baseline: 1.1594x; 1.1594x over previous
//
#include <hip/hip_runtime.h>
#include <hip/hip_bf16.h>

#define BD 8192
#define DD 1024
#define BM 128
#define BN 128
#define BKK 64
#define KSPLIT 4
#define NBLK (64 * 8 * KSPLIT)   // btiles * itiles * ksplit = 2048

typedef __attribute__((ext_vector_type(8))) short short8;
typedef __attribute__((ext_vector_type(4))) float floatx4;

__device__ inline float bf2f(unsigned short u) {
    union { unsigned int u; float f; } un;
    un.u = ((unsigned int)u) << 16;
    return un.f;
}
__device__ inline unsigned short f2bf(float f) {
    union { float f; unsigned int u; } un;
    un.f = f;
    unsigned int u = un.u;
    u += 0x7FFF + ((u >> 16) & 1);   // round-to-nearest-even
    return (unsigned short)(u >> 16);
}

__device__ inline void gld_lds16(const void* g, void* l) {
    __builtin_amdgcn_global_load_lds(
        (const __attribute__((address_space(1))) unsigned int*)g,
        (__attribute__((address_space(3))) unsigned int*)l, 16, 0, 0);
}

// All three normalizations in one launch. Wave-per-row (64 lanes x 4 float4 = 1024 f32).
// blocks [0,2048): z_rna -> rnb (+entropy er), [2048,4096): z_atac -> anb (+ea),
// [4096,4352): link -> linkb (no entropy).
__global__ __launch_bounds__(256) void norm_all(const float* __restrict__ rna,
                                                const float* __restrict__ atac,
                                                const float* __restrict__ link,
                                                unsigned short* __restrict__ rnb,
                                                unsigned short* __restrict__ anb,
                                                unsigned short* __restrict__ linkb,
                                                float* __restrict__ er,
                                                float* __restrict__ ea) {
    int bid = blockIdx.x;
    int wid = threadIdx.x >> 6, lane = threadIdx.x & 63;
    const float* x;
    unsigned short* xb;
    float* ep;
    int row;
    bool ent = true;
    if (bid < 2048)      { x = rna;  xb = rnb;   ep = er + bid;          row = bid * 4 + wid; }
    else if (bid < 4096) { x = atac; xb = anb;   ep = ea + (bid - 2048); row = (bid - 2048) * 4 + wid; }
    else                 { x = link; xb = linkb; ep = nullptr;           row = (bid - 4096) * 4 + wid; ent = false; }

    const float4* xr = (const float4*)(x + (size_t)row * DD);
    float4 v0 = xr[lane];
    float4 v1 = xr[lane + 64];
    float4 v2 = xr[lane + 128];
    float4 v3 = xr[lane + 192];
    float ss = v0.x*v0.x + v0.y*v0.y + v0.z*v0.z + v0.w*v0.w
             + v1.x*v1.x + v1.y*v1.y + v1.z*v1.z + v1.w*v1.w
             + v2.x*v2.x + v2.y*v2.y + v2.z*v2.z + v2.w*v2.w
             + v3.x*v3.x + v3.y*v3.y + v3.z*v3.z + v3.w*v3.w;
#pragma unroll
    for (int off = 1; off < 64; off <<= 1) ss += __shfl_xor(ss, off);
    float inv = 1.0f / fmaxf(sqrtf(ss), 1e-12f);
    ushort4* orow = (ushort4*)(xb + (size_t)row * DD);
    float4 vv[4] = {v0, v1, v2, v3};
    float epart = 0.f;
#pragma unroll
    for (int i = 0; i < 4; ++i) {
        float a = vv[i].x * inv, b = vv[i].y * inv, c = vv[i].z * inv, d = vv[i].w * inv;
        ushort4 o;
        o.x = f2bf(a); o.y = f2bf(b); o.z = f2bf(c); o.w = f2bf(d);
        orow[lane + 64 * i] = o;
        if (ent) {
            epart += a * __logf(a + 1e-8f) + b * __logf(b + 1e-8f)
                   + c * __logf(c + 1e-8f) + d * __logf(d + 1e-8f);
        }
    }
    if (ent) {
#pragma unroll
        for (int off = 1; off < 64; off <<= 1) epart += __shfl_xor(epart, off);
        __shared__ float sw[4];
        if (lane == 0) sw[wid] = epart;
        __syncthreads();
        if (threadIdx.x == 0) ep[0] = sw[0] + sw[1] + sw[2] + sw[3];
    }
}

// Split-K GEMM (K/4 per block), sum-only fused epilogue -> one f32 per block.
// LDS exactly 32KB (As reused for the epilogue reduction) -> 5 blocks/CU resident.
__global__ __launch_bounds__(256) void gemm_cos(const unsigned short* __restrict__ anb,
                                                const unsigned short* __restrict__ linkb,
                                                const unsigned short* __restrict__ rnb,
                                                float* __restrict__ gpart) {
    __shared__ unsigned short As[BM * BKK];
    __shared__ unsigned short Bs[BN * BKK];

    // 2048 blocks = 64 btiles x 8 itiles x 4 ksplits; bid&7 = XCD.
    int bid = blockIdx.x;
    int j = bid >> 3;                      // 0..255
    int btile = (bid & 7) * 8 + (j & 7);   // 0..63
    int itile = (j >> 3) & 7;              // 0..7
    int ks = j >> 6;                       // 0..3
    int b0 = btile * BM;
    int i0 = itile * BN;
    int kbase = ks * (DD / KSPLIT);        // 256

    int tid = threadIdx.x;
    int wid = tid >> 6, lane = tid & 63;
    int wm = wid >> 1, wn = wid & 1;
    int r = lane & 15, kg = lane >> 4;

    // Staging: LDS linear dest; global source column pre-swizzled (rule 21).
    int srow = tid >> 3;
    int scb = (tid & 7) * 16;
    int scb_src = scb ^ ((srow & 7) << 4);

    const char* agbase = (const char*)anb + ((size_t)(b0 + srow) * DD + kbase) * 2 + scb_src;
    const char* bgbase = (const char*)linkb + ((size_t)(i0 + srow) * DD + kbase) * 2 + scb_src;
    unsigned short* al = As + srow * BKK + scb / 2;
    unsigned short* bl = Bs + srow * BKK + scb / 2;

    floatx4 acc[4][4];
#pragma unroll
    for (int m = 0; m < 4; ++m)
#pragma unroll
        for (int n = 0; n < 4; ++n) acc[m][n] = (floatx4)0.0f;

#pragma unroll
    for (int c = 0; c < 4; ++c) {
        gld_lds16(agbase + (size_t)c * 32 * DD * 2, al + c * 2048);
        gld_lds16(bgbase + (size_t)c * 32 * DD * 2, bl + c * 2048);
    }

    for (int step = 0; step < DD / KSPLIT / BKK; ++step) {   // 4 steps
        __syncthreads();
#pragma unroll
        for (int kk = 0; kk < 2; ++kk) {
            short8 a_[4], b_[4];
#pragma unroll
            for (int m = 0; m < 4; ++m) {
                int row = wm * 64 + m * 16 + r;
                int cb = (kg * 16 + kk * 64) ^ ((row & 7) << 4);
                a_[m] = *(const short8*)((const char*)As + row * 128 + cb);
            }
#pragma unroll
            for (int n = 0; n < 4; ++n) {
                int row = wn * 64 + n * 16 + r;
                int cb = (kg * 16 + kk * 64) ^ ((row & 7) << 4);
                b_[n] = *(const short8*)((const char*)Bs + row * 128 + cb);
            }
#pragma unroll
            for (int m = 0; m < 4; ++m)
#pragma unroll
                for (int n = 0; n < 4; ++n)
                    acc[m][n] = __builtin_amdgcn_mfma_f32_16x16x32_bf16(a_[m], b_[n], acc[m][n], 0, 0, 0);
        }
        __syncthreads();
        if (step < DD / KSPLIT / BKK - 1) {
            size_t kb = (size_t)(step + 1) * BKK * 2;
#pragma unroll
            for (int c = 0; c < 4; ++c) {
                gld_lds16(agbase + (size_t)c * 32 * DD * 2 + kb, al + c * 2048);
                gld_lds16(bgbase + (size_t)c * 32 * DD * 2 + kb, bl + c * 2048);
            }
        }
    }

    int b0w = b0 + wm * 64, i0w = i0 + wn * 64;
    float s = 0.f;
#pragma unroll
    for (int m = 0; m < 4; ++m) {
#pragma unroll
        for (int rr = 0; rr < 4; ++rr) {
            const unsigned short* rrow = rnb + (size_t)(b0w + m * 16 + kg * 4 + rr) * DD + i0w + r;
#pragma unroll
            for (int n = 0; n < 4; ++n)
                s += acc[m][n][rr] * bf2f(rrow[n * 16]);
        }
    }
#pragma unroll
    for (int off = 1; off < 64; off <<= 1) s += __shfl_xor(s, off);
    __syncthreads();                    // all waves done with As
    float* swb = (float*)As;            // reuse LDS, keep block at exactly 32KB
    if (lane == 0) swb[wid] = s;
    __syncthreads();
    if (tid == 0) gpart[bid] = swb[0] + swb[1] + swb[2] + swb[3];
}

__global__ __launch_bounds__(256) void finalize(const float* __restrict__ gpart,
                                                const float* __restrict__ er,
                                                const float* __restrict__ ea,
                                                const float* __restrict__ temp,
                                                float* __restrict__ out) {
    __shared__ float sb[4][3];
    float s = 0.f, se = 0.f, sa = 0.f;
    for (int i = threadIdx.x; i < NBLK; i += 256) s += gpart[i];
    for (int i = threadIdx.x; i < 2048; i += 256) { se += er[i]; sa += ea[i]; }
#pragma unroll
    for (int off = 1; off < 64; off <<= 1) {
        s += __shfl_xor(s, off);
        se += __shfl_xor(se, off);
        sa += __shfl_xor(sa, off);
    }
    int wid = threadIdx.x >> 6, lane = threadIdx.x & 63;
    if (lane == 0) { sb[wid][0] = s; sb[wid][1] = se; sb[wid][2] = sa; }
    __syncthreads();
    if (threadIdx.x == 0) {
        float total = sb[0][0] + sb[1][0] + sb[2][0] + sb[3][0];
        float ser = sb[0][1] + sb[1][1] + sb[2][1] + sb[3][1];
        float sea = sb[0][2] + sb[1][2] + sb[2][2] + sb[3][2];
        float ent_rna = -ser / (float)BD;
        float ent_atac = -sea / (float)BD;
        float avg = 0.5f * (ent_rna + ent_atac);
        float t = temp[0];
        float sg = 1.0f / (1.0f + __expf(-t));
        float scale = sg * 0.1f + (1.0f - sg) * avg;
        float tau = fminf(fmaxf(scale, 0.01f), 1.0f);
        out[0] = -(total / (float)BD) / tau;
    }
}

extern "C" void kernel_launch(void* const* d_in, const int* in_sizes, int n_in,
                              void* d_out, int out_size, void* d_ws, size_t ws_size,
                              hipStream_t stream) {
    const float* z_rna = (const float*)d_in[0];
    const float* z_atac = (const float*)d_in[1];
    const float* link = (const float*)d_in[2];
    const float* temp = (const float*)d_in[3];
    float* out = (float*)d_out;

    char* ws = (char*)d_ws;
    float* gpart = (float*)ws;                          // 2048 f32 = 8KB
    float* er_part = (float*)(ws + 8192);               // 2048 f32 = 8KB
    float* ea_part = (float*)(ws + 16384);              // 2048 f32 = 8KB
    unsigned short* linkb = (unsigned short*)(ws + 32768);                       // 2 MB
    unsigned short* rnb = (unsigned short*)(ws + 32768 + 2097152);               // 16 MB
    unsigned short* anb = (unsigned short*)(ws + 32768 + 2097152 + 16777216);    // 16 MB

    // No memset needed: every partial slot is written unconditionally.
    norm_all<<<4352, 256, 0, stream>>>(z_rna, z_atac, link, rnb, anb, linkb, er_part, ea_part);
    gemm_cos<<<NBLK, 256, 0, stream>>>(anb, linkb, rnb, gpart);
    finalize<<<1, 256, 0, stream>>>(gpart, er_part, ea_part, temp, out);
}